// Round 4
// baseline (490.038 us; speedup 1.0000x reference)
//
#include <hip/hip_runtime.h>
#include <hip/hip_fp16.h>
#include <math.h>

#define IN_DIM   128
#define OUT_DIM  128
#define D_TIME   64
#define NSRC     50000
#define NDST     50000
#define NE       800000
#define NPB      40         // nodes per transform block (1250 blocks)
#define GR       4          // nodes per sync round
#define NR       (NPB/GR)   // 10 rounds
#define DPB      16         // dst nodes per dots block (3125 blocks)
#define EPB      256        // edges per score block (3125 blocks)
#define SLOTS    64         // max degree slots per dst (Poisson(16): P(>=64)~1e-19)
#define INV_SCALE 0.05590169943749474f  // 1/sqrt(2*128+64)

// v_d[k] = sum_j W_dst[j][k]*attn[128+j]
__global__ __launch_bounds__(256) void k_prevec(const float* __restrict__ Wd,
                                                const float* __restrict__ attn,
                                                float* __restrict__ v_d){
    int wv = threadIdx.x >> 6, lane = threadIdx.x & 63;
    int k = blockIdx.x * 4 + wv;           // 0..127
    int j = 2 * lane;
    float acc = Wd[(size_t)j*IN_DIM + k] * attn[OUT_DIM + j]
              + Wd[(size_t)(j+1)*IN_DIM + k] * attn[OUT_DIM + j + 1];
    #pragma unroll
    for (int off = 32; off > 0; off >>= 1) acc += __shfl_down(acc, off, 64);
    if (lane == 0) v_d[k] = acc;
}

// Mega front end: three block roles interleaved in stripes of 12
// (2 transform, 5 score, 5 dots) so VALU-bound transform waves and
// HBM-streaming score waves co-reside on every CU.
//   transform (1250): Zh[node]=fp16(W@h_src[node]) AND s_src[node]=Z.a_s
//   score     (3125): pt[e] = phi[e].a_t   (205 MB stream, biggest HBM leg)
//   dots      (3125): s_dst[n] = h_dst[n].v_d  + counts zeroing
__global__ __launch_bounds__(256, 4) void k_mega(const float* __restrict__ h_src,
                                                 const float* __restrict__ h_dst,
                                                 const float* __restrict__ W,
                                                 const float* __restrict__ attn,
                                                 const float* __restrict__ v_d,
                                                 const float* __restrict__ phi,
                                                 __half* __restrict__ Zh,
                                                 float* __restrict__ s_src,
                                                 float* __restrict__ s_dst,
                                                 float* __restrict__ pt,
                                                 int* __restrict__ counts){
    int t = threadIdx.x;
    int stripe = blockIdx.x / 12, rem = blockIdx.x % 12;
    if (rem < 2){
        // ---- transform: 2 per stripe, tb in [0,1250) ----
        __shared__ float hbuf[2][GR][IN_DIM];
        __shared__ float sred[2][4][GR];
        int tb = stripe * 2 + rem;
        int r  = t >> 1;      // output row 0..127
        int kh = t & 1;       // K half
        int wv = t >> 6, lane = t & 63;
        float a_r = attn[r];  // a_s[r]
        float4 wreg[16];
        const float4* wvp = (const float4*)(W + (size_t)r * IN_DIM + kh * 64);
        #pragma unroll
        for (int i = 0; i < 16; ++i) wreg[i] = wvp[i];
        int base = tb * NPB;
        ((float2*)hbuf[0][wv])[lane] =
            ((const float2*)(h_src + (size_t)(base + wv)*IN_DIM))[lane];
        for (int rnd = 0; rnd < NR; ++rnd){
            __syncthreads();
            if (rnd + 1 < NR)
                ((float2*)hbuf[(rnd+1)&1][wv])[lane] =
                    ((const float2*)(h_src + (size_t)(base + (rnd+1)*GR + wv)*IN_DIM))[lane];
            if (rnd > 0 && t < GR){
                int pb = (rnd-1)&1;
                s_src[base + (rnd-1)*GR + t] =
                    0.5f*(sred[pb][0][t]+sred[pb][1][t]+sred[pb][2][t]+sred[pb][3][t]);
            }
            #pragma unroll
            for (int g = 0; g < GR; ++g){
                const float* hc = hbuf[rnd&1][g] + kh*64;
                float acc = 0.f;
                #pragma unroll
                for (int i = 0; i < 16; ++i){
                    float4 w = wreg[i]; int k = i*4;
                    acc += hc[k+0]*w.x + hc[k+1]*w.y + hc[k+2]*w.z + hc[k+3]*w.w;
                }
                acc += __shfl_xor(acc, 1, 64);   // combine K halves
                if (!kh) Zh[(size_t)(base+rnd*GR+g)*OUT_DIM + r] = __float2half_rn(acc);
                float c = acc * a_r;             // both kh copies -> 0.5 factor
                #pragma unroll
                for (int off = 32; off > 0; off >>= 1) c += __shfl_xor(c, off, 64);
                if (lane == 0) sred[rnd&1][wv][g] = c;
            }
        }
        __syncthreads();
        if (t < GR){
            int pb = (NR-1)&1;
            s_src[base + (NR-1)*GR + t] =
                0.5f*(sred[pb][0][t]+sred[pb][1][t]+sred[pb][2][t]+sred[pb][3][t]);
        }
    } else if (rem < 7){
        // ---- score: 5 per stripe, sb in [0,3125). pt[e] = phi[e].a_t ----
        __shared__ float at[D_TIME];
        int sb = stripe * 5 + (rem - 2);
        if (t < D_TIME) at[t] = attn[2*OUT_DIM + t];
        __syncthreads();
        int sub = t & 15, g = t >> 4;           // 16 groups of 16 lanes
        int e0 = sb * EPB + g;
        float a0 = at[sub*4+0], a1 = at[sub*4+1], a2 = at[sub*4+2], a3 = at[sub*4+3];
        #pragma unroll
        for (int pp = 0; pp < 16; pp += 8){
            float4 w[8];
            #pragma unroll
            for (int q = 0; q < 8; ++q)
                w[q] = ((const float4*)(phi + (size_t)(e0 + (pp+q)*16) * D_TIME))[sub];
            #pragma unroll
            for (int q = 0; q < 8; ++q){
                float acc = w[q].x*a0 + w[q].y*a1 + w[q].z*a2 + w[q].w*a3;
                #pragma unroll
                for (int off = 8; off > 0; off >>= 1) acc += __shfl_xor(acc, off, 64);
                if (sub == 0) pt[e0 + (pp+q)*16] = acc;
            }
        }
    } else {
        // ---- dots: 5 per stripe, db in [0,3125). 16 dst nodes each ----
        __shared__ float vd[IN_DIM];
        int db = stripe * 5 + (rem - 7);
        if (t < IN_DIM) vd[t] = v_d[t];
        __syncthreads();
        int wv = t >> 6, lane = t & 63;
        float v0 = vd[2*lane], v1 = vd[2*lane+1];
        int n0 = db * DPB + wv;
        float2 u[4];
        #pragma unroll
        for (int it = 0; it < 4; ++it)
            u[it] = ((const float2*)(h_dst + (size_t)(n0 + it*4)*IN_DIM))[lane];
        #pragma unroll
        for (int it = 0; it < 4; ++it){
            float acc = u[it].x*v0 + u[it].y*v1;
            #pragma unroll
            for (int off = 32; off > 0; off >>= 1) acc += __shfl_down(acc, off, 64);
            if (lane == 0){
                s_dst[n0 + it*4] = acc;
                counts[n0 + it*4] = 0;   // replaces hipMemsetAsync
            }
        }
    }
}

// Slot phase: compose score + leaky + bucket. 2 edges/thread for ILP.
__global__ __launch_bounds__(256) void k_slot(const int* __restrict__ ei,
                                              const float* __restrict__ pt,
                                              const float* __restrict__ s_src,
                                              const float* __restrict__ s_dst,
                                              int2* __restrict__ slots,
                                              int* __restrict__ counts){
    int base = blockIdx.x * 512 + threadIdx.x;
    int srcs[2], dsts[2]; float ptv[2]; bool ok[2];
    #pragma unroll
    for (int q = 0; q < 2; ++q){
        int e = base + q*256;
        ok[q] = (e < NE);
        int ec = ok[q] ? e : 0;
        srcs[q] = ei[ec]; dsts[q] = ei[NE + ec]; ptv[q] = pt[ec];
    }
    float ss[2], sd[2];
    #pragma unroll
    for (int q = 0; q < 2; ++q){ ss[q] = s_src[srcs[q]]; sd[q] = s_dst[dsts[q]]; }
    #pragma unroll
    for (int q = 0; q < 2; ++q){
        if (!ok[q]) continue;
        float v = ss[q] + sd[q] + ptv[q];
        v = (v > 0.f) ? v : 0.2f * v;
        v *= INV_SCALE;
        int k = atomicAdd(&counts[dsts[q]], 1);
        if (k < SLOTS) slots[(dsts[q] << 6) + k] = make_int2(srcs[q], __float_as_int(v));
    }
}

// per-dst softmax + weighted fp16-Z accumulation. One wave per dst, 4 dst/block.
// Gather: half-wave per row (32 lanes x 8B = one 256B row) -> 2 rows/instr.
__global__ __launch_bounds__(256) void k_agg(const int* __restrict__ counts,
                                             const int2* __restrict__ slots,
                                             const __half* __restrict__ Zh,
                                             float* __restrict__ out){
    int wv = threadIdx.x >> 6, lane = threadIdx.x & 63;
    int half = lane >> 5, sl = lane & 31;
    int d = blockIdx.x * 4 + wv;
    int cnt = counts[d]; cnt = (cnt > SLOTS) ? SLOTS : cnt;
    float e = -1e30f; int src = 0;
    if (lane < cnt){
        int2 s = slots[(d << 6) + lane];
        src = s.x; e = __int_as_float(s.y);
    }
    float m = e;
    #pragma unroll
    for (int off = 32; off > 0; off >>= 1) m = fmaxf(m, __shfl_xor(m, off, 64));
    float ex = (lane < cnt) ? __expf(e - m) : 0.f;
    float sum = ex;
    #pragma unroll
    for (int off = 32; off > 0; off >>= 1) sum += __shfl_xor(sum, off, 64);
    float alpha = ex / (sum + 1e-12f);   // lanes >= cnt: exactly 0
    float4 acc4 = make_float4(0.f, 0.f, 0.f, 0.f);
    int jmax = (cnt + 7) & ~7;
    for (int j = 0; j < jmax; j += 8){
        float a[4]; int s[4];
        #pragma unroll
        for (int q = 0; q < 4; ++q){
            int idx = j + 2*q + half;
            a[q] = __shfl(alpha, idx, 64);
            s[q] = __shfl(src,   idx, 64);
        }
        float2 raw[4];
        #pragma unroll
        for (int q = 0; q < 4; ++q)
            raw[q] = ((const float2*)(Zh + (size_t)s[q] * OUT_DIM))[sl];
        #pragma unroll
        for (int q = 0; q < 4; ++q){
            __half2 h0 = *(__half2*)&raw[q].x;
            __half2 h1 = *(__half2*)&raw[q].y;
            float2 f0 = __half22float2(h0);
            float2 f1 = __half22float2(h1);
            acc4.x += a[q]*f0.x; acc4.y += a[q]*f0.y;
            acc4.z += a[q]*f1.x; acc4.w += a[q]*f1.y;
        }
    }
    acc4.x += __shfl_xor(acc4.x, 32, 64);
    acc4.y += __shfl_xor(acc4.y, 32, 64);
    acc4.z += __shfl_xor(acc4.z, 32, 64);
    acc4.w += __shfl_xor(acc4.w, 32, 64);
    if (!half) ((float4*)(out + (size_t)d * OUT_DIM))[sl] = acc4;
}

extern "C" void kernel_launch(void* const* d_in, const int* in_sizes, int n_in,
                              void* d_out, int out_size, void* d_ws, size_t ws_size,
                              hipStream_t stream){
    const float* h_src = (const float*)d_in[0];
    const float* h_dst = (const float*)d_in[1];
    const int*   ei    = (const int*)d_in[2];
    const float* phi   = (const float*)d_in[3];
    const float* Wsrc  = (const float*)d_in[4];
    const float* Wdst  = (const float*)d_in[5];
    const float* attn  = (const float*)d_in[6];
    float* out = (float*)d_out;

    char* p = (char*)d_ws;
    auto alloc = [&](size_t bytes)->char*{
        char* r = p; p += (bytes + 255) / 256 * 256; return r;
    };
    __half* Zh   = (__half*)alloc((size_t)NSRC*OUT_DIM*2);
    float* s_src = (float*)alloc((size_t)NSRC*4);
    float* s_dst = (float*)alloc((size_t)NDST*4);
    float* v_d   = (float*)alloc(128*4);
    float* pt    = (float*)alloc((size_t)NE*4);
    int2*  slots = (int2*)alloc((size_t)NDST*SLOTS*8);
    int*   counts= (int*)alloc((size_t)NDST*4);

    k_prevec<<<32, 256, 0, stream>>>(Wdst, attn, v_d);
    k_mega<<<7500, 256, 0, stream>>>(h_src, h_dst, Wsrc, attn, v_d, phi,
                                     Zh, s_src, s_dst, pt, counts);
    k_slot<<<(NE + 511)/512, 256, 0, stream>>>(ei, pt, s_src, s_dst, slots, counts);
    k_agg<<<NDST/4, 256, 0, stream>>>(counts, slots, Zh, out);
}